// Round 1
// baseline (796.324 us; speedup 1.0000x reference)
//
#include <hip/hip_runtime.h>

#define THREADS 256
#define ROWS_PER_BLOCK 256
#define ROW 25
#define TILE_FLOATS (ROWS_PER_BLOCK * ROW)   // 6400
#define TILE_VEC4 (TILE_FLOATS / 4)          // 1600
#define FULL_K (TILE_VEC4 / THREADS)         // 6 full rounds; remaining 64 vec4 by tid<64

// global->LDS direct copy, 16 bytes per lane, no VGPR round trip
__device__ __forceinline__ void load16_to_lds(const float* g, float* l) {
    __builtin_amdgcn_global_load_lds(
        (const __attribute__((address_space(1))) void*)g,
        (__attribute__((address_space(3))) void*)l,
        16, 0, 0);
}

__launch_bounds__(THREADS, 6)
__global__ void loss_soft_add_kernel(const float* __restrict__ pre,
                                     const float* __restrict__ tar,
                                     float* __restrict__ out, int B) {
    // Single tile: pre staged here, then overwritten in place with softmax outputs.
    __shared__ __attribute__((aligned(16))) float s_pre[TILE_FLOATS];
    __shared__ float s_part[THREADS / 64];

    const int tid  = threadIdx.x;
    const int row0 = blockIdx.x * ROWS_PER_BLOCK;
    const int nrows = min(ROWS_PER_BLOCK, B - row0);
    const int nfloats = nrows * ROW;
    const size_t base = (size_t)row0 * ROW;   // row0 % 4 == 0 -> base % 4 == 0, 16B-aligned ptrs

    // ---- Phase 1: stage pre tile into LDS (direct-to-LDS, coalesced 16B/lane) ----
    if (nfloats == TILE_FLOATS) {
        const float* gp = pre + base;
        #pragma unroll
        for (int k = 0; k < FULL_K; ++k) {
            const int idx = tid + k * THREADS;            // vec4 index
            load16_to_lds(gp + idx * 4, &s_pre[idx * 4]); // linear lane->LDS mapping
        }
        if (tid < TILE_VEC4 - FULL_K * THREADS) {         // last 64 vec4s
            const int idx = tid + FULL_K * THREADS;
            load16_to_lds(gp + idx * 4, &s_pre[idx * 4]);
        }
    } else {
        // Tail tile (not hit for B = 4,000,000, kept correct).
        for (int idx = tid; idx < nfloats; idx += THREADS)
            s_pre[idx] = pre[base + idx];
    }
    __syncthreads();

    // ---- Phase 2: per-row softmax, write 24 outputs back in place ----
    if (tid < nrows) {
        float* rp = &s_pre[tid * ROW];   // lane stride 25 floats: coprime with 32 banks, free
        #pragma unroll
        for (int c = 0; c < 6; ++c) {
            const float x0 = rp[c * 4 + 0];
            const float x1 = rp[c * 4 + 1];
            const float x2 = rp[c * 4 + 2];
            const float x3 = rp[c * 4 + 3];
            const float m = fmaxf(fmaxf(x0, x1), fmaxf(x2, x3));
            const float e0 = __expf(x0 - m);
            const float e1 = __expf(x1 - m);
            const float e2 = __expf(x2 - m);
            const float e3 = __expf(x3 - m);
            const float k3 = 3.0f / (e0 + e1 + e2 + e3);
            rp[c * 4 + 0] = e0 * k3;
            rp[c * 4 + 1] = e1 * k3;
            rp[c * 4 + 2] = e2 * k3;
            rp[c * 4 + 3] = e3 * k3;
            // rp[24] keeps the stale pre value; masked out in phase 3.
        }
    }
    __syncthreads();

    // ---- Phase 3: stream tar from global (float4, coalesced), |out - tar|, mask col 24 ----
    float acc = 0.0f;
    if (nfloats == TILE_FLOATS) {
        const float4* st = (const float4*)(tar + base);
        const float4* so = (const float4*)s_pre;
        #pragma unroll
        for (int k = 0; k <= FULL_K; ++k) {
            const int idx = tid + k * THREADS;
            if (idx < TILE_VEC4) {
                const float4 t = st[idx];
                const float4 o = so[idx];
                unsigned col = (unsigned)(idx * 4) % 25u;
                acc += (col == 24u) ? 0.0f : fabsf(o.x - t.x); col = (col == 24u) ? 0u : col + 1u;
                acc += (col == 24u) ? 0.0f : fabsf(o.y - t.y); col = (col == 24u) ? 0u : col + 1u;
                acc += (col == 24u) ? 0.0f : fabsf(o.z - t.z); col = (col == 24u) ? 0u : col + 1u;
                acc += (col == 24u) ? 0.0f : fabsf(o.w - t.w);
            }
        }
    } else {
        for (int i = tid; i < nfloats; i += THREADS) {
            if ((unsigned)i % 25u != 24u)
                acc += fabsf(s_pre[i] - tar[base + i]);
        }
    }
    acc *= (1.0f / 24.0f);

    // ---- Wave reduction, cross-wave via LDS, one atomic per block ----
    #pragma unroll
    for (int off = 32; off > 0; off >>= 1)
        acc += __shfl_down(acc, off, 64);
    const int wid = tid >> 6, lane = tid & 63;
    if (lane == 0) s_part[wid] = acc;
    __syncthreads();
    if (tid == 0) {
        const float bsum = s_part[0] + s_part[1] + s_part[2] + s_part[3];
        atomicAdd(out, bsum);
    }
}

extern "C" void kernel_launch(void* const* d_in, const int* in_sizes, int n_in,
                              void* d_out, int out_size, void* d_ws, size_t ws_size,
                              hipStream_t stream) {
    const float* pre = (const float*)d_in[0];
    const float* tar = (const float*)d_in[1];
    float* out = (float*)d_out;
    const int B = in_sizes[0] / ROW;   // 4,000,000

    // d_out is re-poisoned to 0xAA before every launch; zero it on-stream.
    hipMemsetAsync(d_out, 0, sizeof(float) * out_size, stream);

    const int blocks = (B + ROWS_PER_BLOCK - 1) / ROWS_PER_BLOCK;  // 15625
    loss_soft_add_kernel<<<blocks, THREADS, 0, stream>>>(pre, tar, out, B);
}

// Round 3
// 724.891 us; speedup vs baseline: 1.0985x; 1.0985x over previous
//
#include <hip/hip_runtime.h>

#define THREADS 256
#define ROWS_PER_BLOCK 256
#define ROW 25
#define TILE_FLOATS (ROWS_PER_BLOCK * ROW)   // 6400
#define TILE_VEC4 (TILE_FLOATS / 4)          // 1600
#define FULL_K (TILE_VEC4 / THREADS)         // 6 full rounds; remaining 64 vec4 by tid<64
#define MAX_BLOCKS 1536                      // 256 CU x 6 resident blocks (LDS-limited)

// global->LDS direct copy, 16 bytes per lane, no VGPR round trip
__device__ __forceinline__ void load16_to_lds(const float* g, float* l) {
    __builtin_amdgcn_global_load_lds(
        (const __attribute__((address_space(1))) void*)g,
        (__attribute__((address_space(3))) void*)l,
        16, 0, 0);
}

__launch_bounds__(THREADS, 6)
__global__ void loss_soft_add_kernel(const float* __restrict__ pre,
                                     const float* __restrict__ tar,
                                     float* __restrict__ out, int B) {
    __shared__ __attribute__((aligned(16))) float s_pre[TILE_FLOATS];
    __shared__ float s_part[THREADS / 64];

    const int tid = threadIdx.x;
    const int ntiles = (B + ROWS_PER_BLOCK - 1) / ROWS_PER_BLOCK;

    float acc = 0.0f;   // raw |diff| sum across all tiles this block handles

    // Persistent grid-stride over tiles: one atomic per BLOCK (not per tile).
    for (int t = blockIdx.x; t < ntiles; t += gridDim.x) {
        const int row0 = t * ROWS_PER_BLOCK;
        const int nrows = min(ROWS_PER_BLOCK, B - row0);
        const int nfloats = nrows * ROW;
        const size_t base = (size_t)row0 * ROW;   // row0 % 4 == 0 -> 16B-aligned vec ptrs

        // Protect s_pre against the previous iteration's phase-3 readers.
        __syncthreads();

        // ---- Phase 1: stage pre tile into LDS (direct-to-LDS, 16B/lane) ----
        if (nfloats == TILE_FLOATS) {
            const float* gp = pre + base;
            #pragma unroll
            for (int k = 0; k < FULL_K; ++k) {
                const int idx = tid + k * THREADS;            // vec4 index
                load16_to_lds(gp + idx * 4, &s_pre[idx * 4]); // linear lane->LDS mapping
            }
            if (tid < TILE_VEC4 - FULL_K * THREADS) {         // last 64 vec4s
                const int idx = tid + FULL_K * THREADS;
                load16_to_lds(gp + idx * 4, &s_pre[idx * 4]);
            }
        } else {
            // Tail tile (not hit for B = 4,000,000, kept correct).
            for (int idx = tid; idx < nfloats; idx += THREADS)
                s_pre[idx] = pre[base + idx];
        }
        __syncthreads();

        // ---- Phase 2: per-row softmax, write 24 outputs back in place ----
        if (tid < nrows) {
            float* rp = &s_pre[tid * ROW];  // lane stride 25 floats (coprime with 32 banks)
            #pragma unroll
            for (int c = 0; c < 6; ++c) {
                const float x0 = rp[c * 4 + 0];
                const float x1 = rp[c * 4 + 1];
                const float x2 = rp[c * 4 + 2];
                const float x3 = rp[c * 4 + 3];
                const float m = fmaxf(fmaxf(x0, x1), fmaxf(x2, x3));
                const float e0 = __expf(x0 - m);
                const float e1 = __expf(x1 - m);
                const float e2 = __expf(x2 - m);
                const float e3 = __expf(x3 - m);
                const float k3 = 3.0f / (e0 + e1 + e2 + e3);
                rp[c * 4 + 0] = e0 * k3;
                rp[c * 4 + 1] = e1 * k3;
                rp[c * 4 + 2] = e2 * k3;
                rp[c * 4 + 3] = e3 * k3;
                // rp[24] keeps the stale pre value; masked out in phase 3.
            }
        }
        __syncthreads();

        // ---- Phase 3: stream tar from global (float4), |out - tar|, mask col 24 ----
        if (nfloats == TILE_FLOATS) {
            const float4* st = (const float4*)(tar + base);
            const float4* so = (const float4*)s_pre;
            #pragma unroll
            for (int k = 0; k <= FULL_K; ++k) {
                const int idx = tid + k * THREADS;
                if (idx < TILE_VEC4) {
                    const float4 tv = st[idx];
                    const float4 ov = so[idx];
                    unsigned col = (unsigned)(idx * 4) % 25u;
                    acc += (col == 24u) ? 0.0f : fabsf(ov.x - tv.x); col = (col == 24u) ? 0u : col + 1u;
                    acc += (col == 24u) ? 0.0f : fabsf(ov.y - tv.y); col = (col == 24u) ? 0u : col + 1u;
                    acc += (col == 24u) ? 0.0f : fabsf(ov.z - tv.z); col = (col == 24u) ? 0u : col + 1u;
                    acc += (col == 24u) ? 0.0f : fabsf(ov.w - tv.w);
                }
            }
        } else {
            for (int i = tid; i < nfloats; i += THREADS) {
                if ((unsigned)i % 25u != 24u)
                    acc += fabsf(s_pre[i] - tar[base + i]);
            }
        }
    }

    acc *= (1.0f / 24.0f);

    // ---- Wave reduction, cross-wave via LDS, ONE atomic per block ----
    #pragma unroll
    for (int off = 32; off > 0; off >>= 1)
        acc += __shfl_down(acc, off, 64);
    const int wid = tid >> 6, lane = tid & 63;
    if (lane == 0) s_part[wid] = acc;
    __syncthreads();
    if (tid == 0) {
        const float bsum = s_part[0] + s_part[1] + s_part[2] + s_part[3];
        atomicAdd(out, bsum);
    }
}

extern "C" void kernel_launch(void* const* d_in, const int* in_sizes, int n_in,
                              void* d_out, int out_size, void* d_ws, size_t ws_size,
                              hipStream_t stream) {
    const float* pre = (const float*)d_in[0];
    const float* tar = (const float*)d_in[1];
    float* out = (float*)d_out;
    const int B = in_sizes[0] / ROW;   // 4,000,000

    // d_out is re-poisoned to 0xAA before every launch; zero it on-stream.
    hipMemsetAsync(d_out, 0, sizeof(float) * out_size, stream);

    const int ntiles = (B + ROWS_PER_BLOCK - 1) / ROWS_PER_BLOCK;  // 15625
    const int blocks = ntiles < MAX_BLOCKS ? ntiles : MAX_BLOCKS;  // 1536 persistent blocks
    loss_soft_add_kernel<<<blocks, THREADS, 0, stream>>>(pre, tar, out, B);
}